// Round 2
// baseline (104.559 us; speedup 1.0000x reference)
//
#include <hip/hip_runtime.h>
#include <hip/hip_bf16.h>

#define BATCH 131072
#define TP 40   // transpose-tile pitch in bf16 elements (32 cols + 8 pad)

typedef __bf16 bf16x8 __attribute__((ext_vector_type(8)));
typedef float floatx4 __attribute__((ext_vector_type(4)));

__device__ __forceinline__ float fast_tanh(float x) {
    // tanh(x) = 1 - 2/(exp(2x)+1); overflow -> inf -> rcp -> 0 -> +1 (correct limit)
    float e = __expf(2.0f * x);
    return 1.0f - 2.0f * __builtin_amdgcn_rcpf(e + 1.0f);
}

__device__ __forceinline__ unsigned int pk_bf16(float lo, float hi) {
    unsigned short a = __builtin_bit_cast(unsigned short, (__bf16)lo);
    unsigned short b = __builtin_bit_cast(unsigned short, (__bf16)hi);
    return (unsigned int)a | ((unsigned int)b << 16);
}
__device__ __forceinline__ float unpk_lo(unsigned int u) {
    return __builtin_bit_cast(float, u << 16);
}
__device__ __forceinline__ float unpk_hi(unsigned int u) {
    return __builtin_bit_cast(float, u & 0xffff0000u);
}

// d_ws element layout (bf16):
// [0,16384)       W2s : B-frag swizzled W2              (GEMM1: h2pre = h1 @ W2)
// [16384,32768)   GTs : B-frag swizzled G^T, G=W2*C^T   (GEMM2: U = a2 @ G^T)
// [32768,36864)   W1s : B-frag swizzled W1, K pad to 32 (GEMM0: h1pre = [z|t] @ W1)
// [36864,38912)   W3s : B-frag swizzled W3, N pad to 16 (GEMM3: dz = h2 @ W3)
// swizzle: idx = ((kb*N + n)*4 + q)*8 + j  <->  B[k = kb*32 + q*8 + j][n]

__global__ void prep_kernel(const float* __restrict__ W1,
                            const float* __restrict__ W2,
                            const float* __restrict__ W3,
                            __bf16* __restrict__ ws) {
    int idx = blockIdx.x * 256 + threadIdx.x;
    if (idx < 16384) {
        int j = idx & 7, q = (idx >> 3) & 3, n = (idx >> 5) & 127, kb = idx >> 12;
        int k = kb * 32 + q * 8 + j;
        ws[idx] = (__bf16)W2[k * 128 + n];
        float c = 0.0f;
        #pragma unroll
        for (int d = 0; d < 8; ++d) c += W3[k * 8 + d] * W1[d * 128 + n];
        ws[16384 + idx] = (__bf16)(W2[n * 128 + k] * c);
    } else if (idx < 20480) {
        int t = idx - 16384;
        int j = t & 7, q = (t >> 3) & 3, n = t >> 5;   // kb==0 only
        int k = q * 8 + j;
        ws[32768 + t] = (k < 9) ? (__bf16)W1[k * 128 + n] : (__bf16)0.0f;
    } else if (idx < 22528) {
        int t = idx - 20480;
        int j = t & 7, q = (t >> 3) & 3, n = (t >> 5) & 15, kb = t >> 9;
        int k = kb * 32 + q * 8 + j;
        ws[36864 + t] = (n < 8) ? (__bf16)W3[k * 8 + n] : (__bf16)0.0f;
    }
}

__global__ __launch_bounds__(256, 3) void cnf_main(
        const float* __restrict__ z, const float* __restrict__ t_ptr,
        const float* __restrict__ b1g, const float* __restrict__ b2g,
        const float* __restrict__ b3g, const __bf16* __restrict__ ws,
        float* __restrict__ out) {
    __shared__ __bf16 sW2s[16384];          // 32 KB
    __shared__ __bf16 sW1s[4096];           // 8 KB
    __shared__ __bf16 sW3s[2048];           // 4 KB
    __shared__ __bf16 tile[4][16 * TP];     // 5 KB, per-wave private 16x32 subtile

    const int tid = threadIdx.x;
    {
        const uint4* srcv = (const uint4*)ws;
        uint4* dW2 = (uint4*)sW2s;
        for (int i = tid; i < 2048; i += 256) dW2[i] = srcv[i];
        uint4* dW1 = (uint4*)sW1s;
        for (int i = tid; i < 512; i += 256) dW1[i] = srcv[4096 + i];
        uint4* dW3 = (uint4*)sW3s;
        dW3[tid] = srcv[4608 + tid];   // 256 uint4 = 4 KB exactly
    }
    __syncthreads();

    const int lane = tid & 63;
    const int w = tid >> 6;
    const int p = lane & 15;       // C/D col, A row (sample), B col
    const int q = lane >> 4;       // quad
    __bf16* T = tile[w];
    const float tval = t_ptr[0];
    const float b3v = (p < 8) ? b3g[p] : 0.0f;
    const bf16x8* W2sv = (const bf16x8*)sW2s;
    const bf16x8* W1sv = (const bf16x8*)sW1s;
    const bf16x8* W3sv = (const bf16x8*)sW3s;
    const bf16x8* GTv  = (const bf16x8*)(ws + 16384);

    // biases into registers (per-lane slice)
    float b1r[8], b2r[8];
    #pragma unroll
    for (int nt = 0; nt < 8; ++nt) {
        b1r[nt] = b1g[nt * 16 + p];
        b2r[nt] = b2g[nt * 16 + p];
    }

    // Build both iterations' X A-frags up front (hides z-load latency)
    bf16x8 axs[2];
    #pragma unroll
    for (int it = 0; it < 2; ++it) {
        bf16x8 ax;
        #pragma unroll
        for (int j = 0; j < 8; ++j) ax[j] = (__bf16)0.0f;
        if (q == 0) {
            const int s = blockIdx.x * 128 + it * 64 + w * 16 + p;
            const float4 z0 = ((const float4*)(z + (size_t)s * 8))[0];
            const float4 z1 = ((const float4*)(z + (size_t)s * 8))[1];
            ax[0] = (__bf16)z0.x; ax[1] = (__bf16)z0.y;
            ax[2] = (__bf16)z0.z; ax[3] = (__bf16)z0.w;
            ax[4] = (__bf16)z1.x; ax[5] = (__bf16)z1.y;
            ax[6] = (__bf16)z1.z; ax[7] = (__bf16)z1.w;
        } else if (q == 1) {
            ax[0] = (__bf16)tval;   // x[8] = t
        }
        axs[it] = ax;
    }

    for (int it = 0; it < 2; ++it) {
        const int s0 = blockIdx.x * 128 + it * 64 + w * 16;

        // ---- GEMM0: h1pre = X @ W1, fused tanh/a1; subtile-interleaved RT ----
        bf16x8 ah[4];
        unsigned int a1p[16];
        #pragma unroll
        for (int kb = 0; kb < 4; ++kb) {
            #pragma unroll
            for (int h = 0; h < 2; ++h) {
                const int nt = 2 * kb + h;
                const int n = nt * 16 + p;
                floatx4 acc = {0.f, 0.f, 0.f, 0.f};
                acc = __builtin_amdgcn_mfma_f32_16x16x32_bf16(axs[it], W1sv[n * 4 + q], acc, 0, 0, 0);
                float a1v[4];
                #pragma unroll
                for (int r = 0; r < 4; ++r) {
                    const float h1 = fast_tanh(acc[r] + b1r[nt]);
                    a1v[r] = __builtin_fmaf(-h1, h1, 1.0f);
                    T[(q * 4 + r) * TP + h * 16 + p] = (__bf16)h1;
                }
                a1p[nt * 2]     = pk_bf16(a1v[0], a1v[1]);
                a1p[nt * 2 + 1] = pk_bf16(a1v[2], a1v[3]);
            }
            ah[kb] = *(const bf16x8*)&T[p * TP + q * 8];  // wave-private, in-order DS
        }

        // ---- GEMM1: h2pre = h1 @ W2 (kb-outer, 8 live accumulators) ----
        floatx4 acc[8];
        #pragma unroll
        for (int nt = 0; nt < 8; ++nt) acc[nt] = (floatx4){0.f, 0.f, 0.f, 0.f};
        #pragma unroll
        for (int kb = 0; kb < 4; ++kb) {
            #pragma unroll
            for (int nt = 0; nt < 8; ++nt)
                acc[nt] = __builtin_amdgcn_mfma_f32_16x16x32_bf16(
                        ah[kb], W2sv[(kb * 128 + nt * 16 + p) * 4 + q], acc[nt], 0, 0, 0);
        }

        // ---- tanh -> h2 subtile RT; GEMM3 partial; aa = 1-h2^2 in regs ----
        bf16x8 av[4];                       // holds ah2, converted in place to aa
        floatx4 acc3 = {0.f, 0.f, 0.f, 0.f};
        #pragma unroll
        for (int kb = 0; kb < 4; ++kb) {
            #pragma unroll
            for (int h = 0; h < 2; ++h) {
                const int nt = 2 * kb + h;
                #pragma unroll
                for (int r = 0; r < 4; ++r) {
                    const float h2 = fast_tanh(acc[nt][r] + b2r[nt]);
                    T[(q * 4 + r) * TP + h * 16 + p] = (__bf16)h2;
                }
            }
            av[kb] = *(const bf16x8*)&T[p * TP + q * 8];
            acc3 = __builtin_amdgcn_mfma_f32_16x16x32_bf16(
                    av[kb], W3sv[(kb * 16 + p) * 4 + q], acc3, 0, 0, 0);
            #pragma unroll
            for (int j = 0; j < 8; ++j) {
                const float h2f = (float)av[kb][j];
                av[kb][j] = (__bf16)__builtin_fmaf(-h2f, h2f, 1.0f);
            }
        }

        // ---- GEMM2: U = a2 @ G^T (kb-outer, acc reused), fused trace dot ----
        #pragma unroll
        for (int nt = 0; nt < 8; ++nt) acc[nt] = (floatx4){0.f, 0.f, 0.f, 0.f};
        #pragma unroll
        for (int kb = 0; kb < 4; ++kb) {
            #pragma unroll
            for (int nt = 0; nt < 8; ++nt)
                acc[nt] = __builtin_amdgcn_mfma_f32_16x16x32_bf16(
                        av[kb], GTv[(kb * 128 + nt * 16 + p) * 4 + q], acc[nt], 0, 0, 0);
        }
        float tr[4] = {0.f, 0.f, 0.f, 0.f};
        #pragma unroll
        for (int nt = 0; nt < 8; ++nt) {
            tr[0] = __builtin_fmaf(unpk_lo(a1p[nt * 2]),     acc[nt][0], tr[0]);
            tr[1] = __builtin_fmaf(unpk_hi(a1p[nt * 2]),     acc[nt][1], tr[1]);
            tr[2] = __builtin_fmaf(unpk_lo(a1p[nt * 2 + 1]), acc[nt][2], tr[2]);
            tr[3] = __builtin_fmaf(unpk_hi(a1p[nt * 2 + 1]), acc[nt][3], tr[3]);
        }

        // ---- dz output ----
        if (p < 8) {
            #pragma unroll
            for (int r = 0; r < 4; ++r)
                out[(size_t)(s0 + q * 4 + r) * 8 + p] = acc3[r] + b3v;
        }

        // ---- trace reduce over the 16 lanes of each quad; write -trace ----
        #pragma unroll
        for (int r = 0; r < 4; ++r) {
            float v = tr[r];
            v += __shfl_xor(v, 1, 64);
            v += __shfl_xor(v, 2, 64);
            v += __shfl_xor(v, 4, 64);
            v += __shfl_xor(v, 8, 64);
            tr[r] = v;
        }
        if (p == 0) {
            #pragma unroll
            for (int r = 0; r < 4; ++r)
                out[(size_t)BATCH * 8 + s0 + q * 4 + r] = -tr[r];
        }
    }
}

extern "C" void kernel_launch(void* const* d_in, const int* in_sizes, int n_in,
                              void* d_out, int out_size, void* d_ws, size_t ws_size,
                              hipStream_t stream) {
    const float* z  = (const float*)d_in[0];
    // d_in[1] = logp_z (unused by the reference math)
    const float* t  = (const float*)d_in[2];
    const float* W1 = (const float*)d_in[3];
    const float* b1 = (const float*)d_in[4];
    const float* W2 = (const float*)d_in[5];
    const float* b2 = (const float*)d_in[6];
    const float* W3 = (const float*)d_in[7];
    const float* b3 = (const float*)d_in[8];
    __bf16* ws = (__bf16*)d_ws;
    float* out = (float*)d_out;

    prep_kernel<<<88, 256, 0, stream>>>(W1, W2, W3, ws);
    cnf_main<<<1024, 256, 0, stream>>>(z, t, b1, b2, b3, ws, out);
}